// Round 1
// baseline (1569.018 us; speedup 1.0000x reference)
//
#include <hip/hip_runtime.h>
#include <hip/hip_bf16.h>

#define GN 50000
#define GE 600000
#define DD 128
#define TQ 2048          // RBF table quantization (2049 rows)
#define NBOND 2268       // 12*27*7 bond combo rows
#define ECH 32           // edges per chunk in edge kernel

// ---------------------------------------------------------------- atom encoder
__global__ __launch_bounds__(256) void atom_kernel(
    const int* __restrict__ x, const int* __restrict__ atom_off,
    const float* __restrict__ atom_emb, float* __restrict__ h)
{
    int t = blockIdx.x * 256 + threadIdx.x;
    if (t >= GN * DD) return;
    int n = t >> 7, d = t & 127;
    float s = 0.f;
#pragma unroll
    for (int f = 0; f < 9; f++) {
        int idx = x[n * 9 + f] + atom_off[f];
        s += atom_emb[idx * DD + d];
    }
    h[t] = s;
}

// ---------------------------------------------------------------- CSR build
__global__ __launch_bounds__(256) void hist_kernel(const int* __restrict__ ei, int* __restrict__ count)
{
    int e = blockIdx.x * 256 + threadIdx.x;
    if (e < GE) atomicAdd(&count[ei[GE + e]], 1);
}

__global__ __launch_bounds__(1024) void scan_kernel(const int* __restrict__ count, int* __restrict__ row_start)
{
    __shared__ int part[1024];
    int t = threadIdx.x;
    const int PER = (GN + 1023) / 1024;   // 49
    int base = t * PER;
    int s = 0;
    for (int i = 0; i < PER; i++) { int idx = base + i; if (idx < GN) s += count[idx]; }
    part[t] = s;
    __syncthreads();
    for (int off = 1; off < 1024; off <<= 1) {
        int v = (t >= off) ? part[t - off] : 0;
        __syncthreads();
        part[t] += v;
        __syncthreads();
    }
    int run = (t == 0) ? 0 : part[t - 1];
    for (int i = 0; i < PER; i++) {
        int idx = base + i;
        if (idx < GN) { row_start[idx] = run; run += count[idx]; }
        else if (idx == GN) { row_start[idx] = run; }
    }
}

__global__ __launch_bounds__(256) void scatter_kernel(
    const int* __restrict__ ei, const int* __restrict__ row_start,
    int* __restrict__ fill, int* __restrict__ csr)
{
    int e = blockIdx.x * 256 + threadIdx.x;
    if (e < GE) {
        int d = ei[GE + e];
        int p = row_start[d] + atomicAdd(&fill[d], 1);
        csr[p] = e;
    }
}

// ---------------------------------------------------------------- per-layer tables
// tbl_bl[q][d] = b_bl[d]+b_pr[d] + sum_k exp(-10(xq-0.1k)^2) W_bl[k][d],  xq = q/TQ
// tbl_pr[q][d] =                   sum_k exp(-(xq-0.05k)^2)  W_pr[k][d]
// tbl_bond[(b0*27+b1)*7+b2][d] = sum of the 3 bond embedding rows
__global__ __launch_bounds__(128) void tables_kernel(
    const float* __restrict__ W_bl_l, const float* __restrict__ b_bl_l,
    const float* __restrict__ W_pr_l, const float* __restrict__ b_pr_l,
    const float* __restrict__ bond_emb_l, const int* __restrict__ bond_off,
    float* __restrict__ tbl_bl, float* __restrict__ tbl_pr, float* __restrict__ tbl_bond)
{
    int b = blockIdx.x, d = threadIdx.x;
    if (b < (TQ + 1)) {
        float xq = b * (1.0f / TQ);
        float s = b_bl_l[d] + b_pr_l[d];
#pragma unroll
        for (int k = 0; k < 20; k++) {
            float dl = xq - 0.1f * k;
            s += __expf(-10.f * dl * dl) * W_bl_l[k * DD + d];
        }
        tbl_bl[b * DD + d] = s;
    } else if (b < 2 * (TQ + 1)) {
        int q = b - (TQ + 1);
        float xq = q * (1.0f / TQ);
        float s = 0.f;
#pragma unroll
        for (int k = 0; k < 20; k++) {
            float dl = xq - 0.05f * k;
            s += __expf(-dl * dl) * W_pr_l[k * DD + d];
        }
        tbl_pr[q * DD + d] = s;
    } else {
        int r = b - 2 * (TQ + 1);
        int b0 = r / (27 * 7);
        int rem = r % (27 * 7);
        int b1 = rem / 7, b2 = rem % 7;
        tbl_bond[r * DD + d] = bond_emb_l[(b0 + bond_off[0]) * DD + d]
                             + bond_emb_l[(b1 + bond_off[1]) * DD + d]
                             + bond_emb_l[(b2 + bond_off[2]) * DD + d];
    }
}

// ---------------------------------------------------------------- edge/aggregate
// one block (128 threads) per node n: A[n] = (1+eps)h[n] + sum_{e: dst=n} relu(h[src]+e_edge)
__global__ __launch_bounds__(128) void edge_kernel(
    const int* __restrict__ ei, const int* __restrict__ eai, const float* __restrict__ eaf,
    const float* __restrict__ tbl_bl, const float* __restrict__ tbl_pr, const float* __restrict__ tbl_bond,
    const float* __restrict__ h, const int* __restrict__ row_start, const int* __restrict__ csr,
    const float* __restrict__ eps_gin, int layer,
    float* __restrict__ A, float* __restrict__ stats)
{
    int n = blockIdx.x;
    int d = threadIdx.x;
    if (n == 0) {   // zero BN-stat accumulators for this layer (runs before G1/G2)
        stats[d] = 0.f; stats[DD + d] = 0.f; stats[2 * DD + d] = 0.f; stats[3 * DD + d] = 0.f;
    }
    __shared__ int msrc[ECH], mq1[ECH], mq2[ECH], mb[ECH];
    int s0 = row_start[n], s1 = row_start[n + 1];
    float acc = 0.f;
    for (int base = s0; base < s1; base += ECH) {
        int cnt = min(ECH, s1 - base);
        __syncthreads();
        if (d < cnt) {
            int eid = csr[base + d];
            msrc[d] = ei[eid];
            float x1 = eaf[eid * 2 + 0];
            float x2 = eaf[eid * 2 + 1];
            int q1 = (int)(x1 * (float)TQ + 0.5f); q1 = min(max(q1, 0), TQ);
            int q2 = (int)(x2 * (float)TQ + 0.5f); q2 = min(max(q2, 0), TQ);
            mq1[d] = q1; mq2[d] = q2;
            int b0 = eai[eid * 3 + 0], b1 = eai[eid * 3 + 1], b2 = eai[eid * 3 + 2];
            b0 = min(max(b0, 0), 11); b1 = min(max(b1, 0), 26); b2 = min(max(b2, 0), 6);
            mb[d] = (b0 * 27 + b1) * 7 + b2;
        }
        __syncthreads();
        for (int ce = 0; ce < cnt; ce++) {
            float e = tbl_bl[mq1[ce] * DD + d] + tbl_pr[mq2[ce] * DD + d] + tbl_bond[mb[ce] * DD + d];
            float m = h[(size_t)msrc[ce] * DD + d] + e;
            acc += fmaxf(m, 0.f);
        }
    }
    float eps1 = 1.0f + eps_gin[layer];
    A[(size_t)n * DD + d] = eps1 * h[(size_t)n * DD + d] + acc;
}

// ---------------------------------------------------------------- fused GEMM (+BN stats)
// MODE 0:  C = A @ W + bias              ; stats_out += column {sum, sumsq} of C
// MODE 1:  C = relu(bn1(A)) @ W + bias   ; bn1 from stats_in (+g,b); stats_out same
template <int MODE>
__global__ __launch_bounds__(256) void gemm_kernel(
    const float* __restrict__ Abuf, const float* __restrict__ W, const float* __restrict__ bias,
    float* __restrict__ C,
    const float* __restrict__ stats_in, const float* __restrict__ bn_g, const float* __restrict__ bn_b,
    float* __restrict__ stats_out)
{
    __shared__ float As[64][32];
    __shared__ float Ws[32][DD];
    __shared__ float red[8][DD];
    __shared__ float sc_s[DD], tr_s[DD];

    int tid = threadIdx.x;
    int row0 = blockIdx.x * 64;

    if (MODE == 1) {
        if (tid < DD) {
            float m = stats_in[tid] * (1.0f / GN);
            float v = stats_in[DD + tid] * (1.0f / GN) - m * m;
            float sc = bn_g[tid] * rsqrtf(v + 1e-5f);
            sc_s[tid] = sc;
            tr_s[tid] = bn_b[tid] - m * sc;
        }
    }

    int tr = tid >> 5;    // 0..7  (8 row groups of 8)
    int tc = tid & 31;    // 0..31 (32 col groups of 4)
    float acc[8][4];
#pragma unroll
    for (int r = 0; r < 8; r++)
#pragma unroll
        for (int c = 0; c < 4; c++) acc[r][c] = 0.f;

    for (int k0 = 0; k0 < DD; k0 += 32) {
        __syncthreads();
        // stage A tile 64x32 (apply bn1+relu transform for MODE 1)
#pragma unroll
        for (int i = 0; i < 2; i++) {
            int slot = tid + 256 * i;           // 0..511
            int r = slot >> 3;
            int kq = slot & 7;
            int gr = row0 + r;
            float4 v;
            if (gr < GN) {
                v = *(const float4*)(Abuf + (size_t)gr * DD + k0 + kq * 4);
                if (MODE == 1) {
                    int kk = k0 + kq * 4;
                    v.x = fmaxf(v.x * sc_s[kk + 0] + tr_s[kk + 0], 0.f);
                    v.y = fmaxf(v.y * sc_s[kk + 1] + tr_s[kk + 1], 0.f);
                    v.z = fmaxf(v.z * sc_s[kk + 2] + tr_s[kk + 2], 0.f);
                    v.w = fmaxf(v.w * sc_s[kk + 3] + tr_s[kk + 3], 0.f);
                }
            } else {
                v = make_float4(0.f, 0.f, 0.f, 0.f);
            }
            *(float4*)(&As[r][kq * 4]) = v;
        }
        // stage W tile 32x128
#pragma unroll
        for (int i = 0; i < 4; i++) {
            int slot = tid + 256 * i;           // 0..1023
            int kr = slot >> 5;
            int cq = slot & 31;
            *(float4*)(&Ws[kr][cq * 4]) = *(const float4*)(W + (size_t)(k0 + kr) * DD + cq * 4);
        }
        __syncthreads();
#pragma unroll
        for (int kq = 0; kq < 8; kq++) {
            float wv[4][4];
#pragma unroll
            for (int j = 0; j < 4; j++) {
                float4 t4 = *(const float4*)(&Ws[kq * 4 + j][tc * 4]);
                wv[j][0] = t4.x; wv[j][1] = t4.y; wv[j][2] = t4.z; wv[j][3] = t4.w;
            }
#pragma unroll
            for (int r = 0; r < 8; r++) {
                float4 av = *(const float4*)(&As[tr * 8 + r][kq * 4]);
#pragma unroll
                for (int c = 0; c < 4; c++) {
                    acc[r][c] += av.x * wv[0][c] + av.y * wv[1][c] + av.z * wv[2][c] + av.w * wv[3][c];
                }
            }
        }
    }

    // epilogue: bias, store, per-column BN stats
    float bcol[4];
#pragma unroll
    for (int c = 0; c < 4; c++) bcol[c] = bias[tc * 4 + c];
    float ps[4] = {0.f, 0.f, 0.f, 0.f}, pq[4] = {0.f, 0.f, 0.f, 0.f};
#pragma unroll
    for (int r = 0; r < 8; r++) {
        int gr = row0 + tr * 8 + r;
        if (gr < GN) {
            float o[4];
#pragma unroll
            for (int c = 0; c < 4; c++) {
                o[c] = acc[r][c] + bcol[c];
                ps[c] += o[c];
                pq[c] += o[c] * o[c];
            }
            float4 v4 = make_float4(o[0], o[1], o[2], o[3]);
            *(float4*)(C + (size_t)gr * DD + tc * 4) = v4;
        }
    }
    __syncthreads();
#pragma unroll
    for (int c = 0; c < 4; c++) red[tr][tc * 4 + c] = ps[c];
    __syncthreads();
    if (tid < DD) {
        float s = 0.f;
#pragma unroll
        for (int i = 0; i < 8; i++) s += red[i][tid];
        atomicAdd(&stats_out[tid], s);
    }
    __syncthreads();
#pragma unroll
    for (int c = 0; c < 4; c++) red[tr][tc * 4 + c] = pq[c];
    __syncthreads();
    if (tid < DD) {
        float s = 0.f;
#pragma unroll
        for (int i = 0; i < 8; i++) s += red[i][tid];
        atomicAdd(&stats_out[DD + tid], s);
    }
}

// ---------------------------------------------------------------- BN2 apply (+relu)
__global__ __launch_bounds__(256) void bn_apply_kernel(
    const float* __restrict__ Z, const float* __restrict__ stats2,
    const float* __restrict__ g, const float* __restrict__ b,
    float* __restrict__ out, int do_relu)
{
    int t = blockIdx.x * 256 + threadIdx.x;
    if (t >= GN * DD) return;
    int c = t & 127;
    float m = stats2[c] * (1.0f / GN);
    float v = stats2[DD + c] * (1.0f / GN) - m * m;
    float sc = g[c] * rsqrtf(v + 1e-5f);
    float tr = b[c] - m * sc;
    float val = Z[t] * sc + tr;
    if (do_relu) val = fmaxf(val, 0.f);
    out[t] = val;
}

// ---------------------------------------------------------------- host launcher
extern "C" void kernel_launch(void* const* d_in, const int* in_sizes, int n_in,
                              void* d_out, int out_size, void* d_ws, size_t ws_size,
                              hipStream_t stream)
{
    const int*   x        = (const int*)d_in[0];
    const int*   ei       = (const int*)d_in[1];
    const int*   eai      = (const int*)d_in[2];
    const float* eaf      = (const float*)d_in[3];
    const int*   atom_off = (const int*)d_in[4];
    const int*   bond_off = (const int*)d_in[5];
    const float* atom_emb = (const float*)d_in[6];
    const float* bond_emb = (const float*)d_in[7];
    const float* W_bl     = (const float*)d_in[8];
    const float* b_bl     = (const float*)d_in[9];
    const float* W_pr     = (const float*)d_in[10];
    const float* b_pr     = (const float*)d_in[11];
    const float* W1       = (const float*)d_in[12];
    const float* b1       = (const float*)d_in[13];
    const float* bn1g     = (const float*)d_in[14];
    const float* bn1b     = (const float*)d_in[15];
    const float* W2       = (const float*)d_in[16];
    const float* b2       = (const float*)d_in[17];
    const float* eps_gin  = (const float*)d_in[18];
    const float* bng      = (const float*)d_in[19];
    const float* bnb      = (const float*)d_in[20];
    float* out = (float*)d_out;

    char* p = (char*)d_ws;
    float* h    = (float*)p;  p += (size_t)GN * DD * 4;
    float* A    = (float*)p;  p += (size_t)GN * DD * 4;   // also reused as z2
    float* z1   = (float*)p;  p += (size_t)GN * DD * 4;
    float* tbl_bl   = (float*)p;  p += (size_t)(TQ + 1) * DD * 4;
    float* tbl_pr   = (float*)p;  p += (size_t)(TQ + 1) * DD * 4;
    float* tbl_bond = (float*)p;  p += (size_t)NBOND * DD * 4;
    float* stats    = (float*)p;  p += 4 * DD * 4;        // [sum1,sumsq1,sum2,sumsq2]
    int* count      = (int*)p;    p += (size_t)GN * 4;
    int* fill       = (int*)p;    p += (size_t)GN * 4;
    int* row_start  = (int*)p;    p += (size_t)(GN + 1) * 4;
    int* csr        = (int*)p;    p += (size_t)GE * 4;

    hipMemsetAsync(count, 0, (size_t)GN * 4, stream);
    hipMemsetAsync(fill,  0, (size_t)GN * 4, stream);

    hist_kernel<<<(GE + 255) / 256, 256, 0, stream>>>(ei, count);
    scan_kernel<<<1, 1024, 0, stream>>>(count, row_start);
    scatter_kernel<<<(GE + 255) / 256, 256, 0, stream>>>(ei, row_start, fill, csr);
    atom_kernel<<<(GN * DD + 255) / 256, 256, 0, stream>>>(x, atom_off, atom_emb, h);

    const int TBLOCKS = 2 * (TQ + 1) + NBOND;
    for (int l = 0; l < 5; l++) {
        tables_kernel<<<TBLOCKS, 128, 0, stream>>>(
            W_bl + (size_t)l * 20 * DD, b_bl + (size_t)l * DD,
            W_pr + (size_t)l * 20 * DD, b_pr + (size_t)l * DD,
            bond_emb + (size_t)l * 46 * DD, bond_off,
            tbl_bl, tbl_pr, tbl_bond);

        edge_kernel<<<GN, 128, 0, stream>>>(
            ei, eai, eaf, tbl_bl, tbl_pr, tbl_bond, h, row_start, csr,
            eps_gin, l, A, stats);

        gemm_kernel<0><<<(GN + 63) / 64, 256, 0, stream>>>(
            A, W1 + (size_t)l * DD * DD, b1 + (size_t)l * DD, z1,
            nullptr, nullptr, nullptr, stats);

        gemm_kernel<1><<<(GN + 63) / 64, 256, 0, stream>>>(
            z1, W2 + (size_t)l * DD * DD, b2 + (size_t)l * DD, A,
            stats, bn1g + (size_t)l * DD, bn1b + (size_t)l * DD, stats + 2 * DD);

        bn_apply_kernel<<<(GN * DD + 255) / 256, 256, 0, stream>>>(
            A, stats + 2 * DD, bng + (size_t)l * DD, bnb + (size_t)l * DD,
            (l < 4) ? h : out, (l < 4) ? 1 : 0);
    }
}